// Round 21
// baseline (41.713 us; speedup 1.0000x reference)
//
#include <hip/hip_runtime.h>
#include <hip/hip_bf16.h>

// SpatialAttention2D MFMA v20: B=2, C=64, N=4096, 4 heads x d=16, fp32 io.
// Unbundling r20's regression: attn reverted BYTE-IDENTICAL to v18 (35.43
// best: unroll 4, K=32 PV, ones-MFMA lsum); qkv keeps v19's 2-token form.
// Clean A/B: if r20's regression was attn full-unroll (spill from hoisted
// prefetch loads), this lands ~35.0-35.8; if ~41, qkv-2tok was the culprit.

#define NTOK 4096
#define HD   16
#define BH   8
#define QUART 1024             // keys per wave (key-quarter)
#define PITERS (QUART/32)      // 32 pair-iters (2 chunks of 16 keys each)

typedef __attribute__((ext_vector_type(4))) short short4v;
typedef __attribute__((ext_vector_type(8))) short short8v;
typedef __attribute__((ext_vector_type(4))) float float4v;
typedef __attribute__((ext_vector_type(4))) ushort ushort4v;
typedef __attribute__((ext_vector_type(2))) unsigned uint2v;

__device__ __forceinline__ ushort f2bf(float f) {
  unsigned u = __builtin_bit_cast(unsigned, f);
  u += 0x7fffu + ((u >> 16) & 1u);          // round-to-nearest-even
  return (ushort)(u >> 16);
}

__device__ __forceinline__ float fast_exp2(float x) {
#if __has_builtin(__builtin_amdgcn_exp2f)
  return __builtin_amdgcn_exp2f(x);
#else
  return exp2f(x);
#endif
}

// packed f32x4 -> bf16x4 (RNE) via v_cvt_pk_bf16_f32 (v6b-verified form)
__device__ __forceinline__ short4v pack4_bf16(float a, float b, float c, float d) {
  __hip_bfloat162 lo = __float22bfloat162_rn(make_float2(a, b));
  __hip_bfloat162 hi = __float22bfloat162_rn(make_float2(c, d));
  unsigned ulo, uhi;
  __builtin_memcpy(&ulo, &lo, 4);
  __builtin_memcpy(&uhi, &hi, 4);
  uint2v u = { ulo, uhi };
  return __builtin_bit_cast(short4v, u);
}

// ws layout in ushort elements (3 MB total)
// Qt: [bh][d][n] (transposed).
// Kp (pair-frag): element (key n, d) at unit (n>>5)*512 +
//     ((d>>2)*16 + (n&15))*8 + ((n>>4)&1)*4 + (d&3)
// Vp (pair-frag): element (d, key n) at unit (n>>5)*512 +
//     (((n&15)>>2)*16 + d)*8 + ((n>>4)&1)*4 + (n&3)
// Both: lane l, pair-iter i reads 16B at i*512 + l*8 = [even frag | odd frag].
#define QB_OFF 0
#define KB_OFF ((size_t)BH*NTOK*HD)
#define VT_OFF (2*(size_t)BH*NTOK*HD)

// ---------------------------------------------------------------------------
// Kernel 1: QKV projection, 2 tokens/thread (v19 form).
// Grid = 12 gg x 64 tg = 768 blocks x 256 threads.
// ---------------------------------------------------------------------------
__global__ __launch_bounds__(256) void qkv_proj(
    const float* __restrict__ x, const float* __restrict__ w,
    const float* __restrict__ bias, ushort* __restrict__ wsu) {
  int tg   = blockIdx.x & 63;      // token group (128 tokens); same tg -> same XCD
  int gg   = blockIdx.x >> 6;      // 0..11: 16-channel slice
  int part = gg >> 2;              // 0=q,1=k,2=v
  int h    = gg & 3;
  int lane = threadIdx.x & 63;
  int dg   = threadIdx.x >> 6;     // 0..3: d-subgroup
  int t0   = tg*128 + lane;        // global token 0..8191
  int b    = t0 >> 12;
  int np0  = t0 & 4095;
  int np1  = np0 + 64;
  int bh   = b*4 + h;
  const float QSCALE = 0.25f * 1.44269504f;

  __shared__ float4 wls[16][16];   // 16 channels x 64 floats = 4 KB
  __shared__ float  bls[16];

  {
    const float4* wg = reinterpret_cast<const float4*>(w + (size_t)gg*16*64);
    wls[threadIdx.x >> 4][threadIdx.x & 15] = wg[threadIdx.x];
    if (threadIdx.x < 16) bls[threadIdx.x] = bias[gg*16 + threadIdx.x];
  }
  __syncthreads();

  float aA0 = bls[dg*4+0], aA1 = bls[dg*4+1];
  float aA2 = bls[dg*4+2], aA3 = bls[dg*4+3];
  float aB0 = aA0, aB1 = aA1, aB2 = aA2, aB3 = aA3;
  const float* xp = x + ((size_t)b*64)*NTOK + np0;

  #pragma unroll
  for (int cc = 0; cc < 4; ++cc) {
    float xrA[16], xrB[16];
    #pragma unroll
    for (int i = 0; i < 16; ++i) {
      xrA[i] = xp[(size_t)(cc*16 + i)*NTOK];
      xrB[i] = xp[(size_t)(cc*16 + i)*NTOK + 64];
    }
    #pragma unroll
    for (int i4 = 0; i4 < 4; ++i4) {
      float4 w0 = wls[dg*4+0][cc*4+i4];
      float4 w1 = wls[dg*4+1][cc*4+i4];
      float4 w2 = wls[dg*4+2][cc*4+i4];
      float4 w3 = wls[dg*4+3][cc*4+i4];
      aA0 = fmaf(xrA[i4*4+0], w0.x, aA0); aA0 = fmaf(xrA[i4*4+1], w0.y, aA0);
      aA0 = fmaf(xrA[i4*4+2], w0.z, aA0); aA0 = fmaf(xrA[i4*4+3], w0.w, aA0);
      aA1 = fmaf(xrA[i4*4+0], w1.x, aA1); aA1 = fmaf(xrA[i4*4+1], w1.y, aA1);
      aA1 = fmaf(xrA[i4*4+2], w1.z, aA1); aA1 = fmaf(xrA[i4*4+3], w1.w, aA1);
      aA2 = fmaf(xrA[i4*4+0], w2.x, aA2); aA2 = fmaf(xrA[i4*4+1], w2.y, aA2);
      aA2 = fmaf(xrA[i4*4+2], w2.z, aA2); aA2 = fmaf(xrA[i4*4+3], w2.w, aA2);
      aA3 = fmaf(xrA[i4*4+0], w3.x, aA3); aA3 = fmaf(xrA[i4*4+1], w3.y, aA3);
      aA3 = fmaf(xrA[i4*4+2], w3.z, aA3); aA3 = fmaf(xrA[i4*4+3], w3.w, aA3);
      aB0 = fmaf(xrB[i4*4+0], w0.x, aB0); aB0 = fmaf(xrB[i4*4+1], w0.y, aB0);
      aB0 = fmaf(xrB[i4*4+2], w0.z, aB0); aB0 = fmaf(xrB[i4*4+3], w0.w, aB0);
      aB1 = fmaf(xrB[i4*4+0], w1.x, aB1); aB1 = fmaf(xrB[i4*4+1], w1.y, aB1);
      aB1 = fmaf(xrB[i4*4+2], w1.z, aB1); aB1 = fmaf(xrB[i4*4+3], w1.w, aB1);
      aB2 = fmaf(xrB[i4*4+0], w2.x, aB2); aB2 = fmaf(xrB[i4*4+1], w2.y, aB2);
      aB2 = fmaf(xrB[i4*4+2], w2.z, aB2); aB2 = fmaf(xrB[i4*4+3], w2.w, aB2);
      aB3 = fmaf(xrB[i4*4+0], w3.x, aB3); aB3 = fmaf(xrB[i4*4+1], w3.y, aB3);
      aB3 = fmaf(xrB[i4*4+2], w3.z, aB3); aB3 = fmaf(xrB[i4*4+3], w3.w, aB3);
    }
  }

  int dd0 = dg*4;
#define STORE_QKV(np_, A0, A1, A2, A3) do {                                 \
    if (part == 0) {                                                        \
      ushort* Qt = wsu + QB_OFF + (size_t)bh*HD*NTOK + (np_);               \
      Qt[(size_t)(dd0+0)*NTOK] = f2bf((A0)*QSCALE);                         \
      Qt[(size_t)(dd0+1)*NTOK] = f2bf((A1)*QSCALE);                         \
      Qt[(size_t)(dd0+2)*NTOK] = f2bf((A2)*QSCALE);                         \
      Qt[(size_t)(dd0+3)*NTOK] = f2bf((A3)*QSCALE);                         \
    } else if (part == 1) {                                                 \
      size_t idx = (size_t)bh*NTOK*HD + (size_t)((np_) >> 5)*512            \
                 + ((dd0 >> 2)*16 + ((np_) & 15))*8 + (((np_) >> 4) & 1)*4; \
      ushort4v vv = { f2bf(A0), f2bf(A1), f2bf(A2), f2bf(A3) };             \
      *(ushort4v*)(wsu + KB_OFF + idx) = vv;                                \
    } else {                                                                \
      size_t base = (size_t)bh*NTOK*HD + (size_t)((np_) >> 5)*512           \
                  + (((np_) >> 4) & 1)*4 + ((np_) & 3);                     \
      ushort* Vp = wsu + VT_OFF + base;                                     \
      Vp[((((np_) & 15) >> 2)*16 + dd0+0)*8] = f2bf(A0);                    \
      Vp[((((np_) & 15) >> 2)*16 + dd0+1)*8] = f2bf(A1);                    \
      Vp[((((np_) & 15) >> 2)*16 + dd0+2)*8] = f2bf(A2);                    \
      Vp[((((np_) & 15) >> 2)*16 + dd0+3)*8] = f2bf(A3);                    \
    } } while (0)

  STORE_QKV(np0, aA0, aA1, aA2, aA3);
  STORE_QKV(np1, aB0, aB1, aB2, aB3);
#undef STORE_QKV
}

// ---------------------------------------------------------------------------
// Kernel 2: register-direct MFMA flash attention; K=32 PV + ones-MFMA lsum.
// BYTE-IDENTICAL to v18 (35.43 best): #pragma unroll 4 pipeline, depth-2.
// Grid = 8 bh x 128 qblk(32q) = 1024 blocks x 256 threads (4 waves).
// ---------------------------------------------------------------------------
__global__ __launch_bounds__(256, 4) void attn_mfma(
    const ushort* __restrict__ wsu, float* __restrict__ out) {
  const ushort* Qt = wsu + QB_OFF;
  const ushort* Kp = wsu + KB_OFF;
  const ushort* Vp = wsu + VT_OFF;

  int bh    = blockIdx.x >> 7;
  int qblk  = blockIdx.x & 127;
  int tid   = threadIdx.x;
  int quart = tid >> 6;            // 0..3: key-quarter
  int lane  = tid & 63;
  int lr    = lane & 15;
  int g4    = (lane >> 4) << 2;
  int qbase = qblk*32;

  __shared__ float comb[3][64][11];   // 8.4 KB epilogue combine

  const ushort* Qh = Qt + (size_t)bh*HD*NTOK;                       // [d][n]
  const ushort* KhF = Kp + (size_t)bh*NTOK*HD + (size_t)quart*QUART*HD;
  const ushort* VhF = Vp + (size_t)bh*NTOK*HD + (size_t)quart*QUART*HD;

  // Q fragments (B operand): lane l holds Q[q][d=g4..g4+3], q-groups 0/1
  short4v qf0, qf1;
  #pragma unroll
  for (int j = 0; j < 4; ++j) {
    qf0[j] = (short)Qh[(size_t)(g4+j)*NTOK + qbase      + lr];
    qf1[j] = (short)Qh[(size_t)(g4+j)*NTOK + qbase + 16 + lr];
  }

  // per-lane 16B pair-fragment pointers; pair-iter i reads at i*512 (ushorts)
  const ushort* kp16 = KhF + lane*8;
  const ushort* vp16 = VhF + lane*8;

  const short8v ones8 = {(short)0x3F80, (short)0x3F80, (short)0x3F80, (short)0x3F80,
                         (short)0x3F80, (short)0x3F80, (short)0x3F80, (short)0x3F80};

  float4v a0 = {0.f,0.f,0.f,0.f}, a1 = {0.f,0.f,0.f,0.f};
  float4v lac0 = {0.f,0.f,0.f,0.f}, lac1 = {0.f,0.f,0.f,0.f};

#define ITER(kpr, vpr)                                                      \
  do {                                                                      \
    short4v ke = __builtin_shufflevector(kpr, kpr, 0,1,2,3);                \
    short4v ko = __builtin_shufflevector(kpr, kpr, 4,5,6,7);                \
    float4v zero = {0.f,0.f,0.f,0.f};                                       \
    __builtin_amdgcn_s_setprio(1);                                          \
    float4v s0e = __builtin_amdgcn_mfma_f32_16x16x16bf16_1k(ke, qf0, zero, 0,0,0); \
    float4v s0o = __builtin_amdgcn_mfma_f32_16x16x16bf16_1k(ko, qf0, zero, 0,0,0); \
    float4v s1e = __builtin_amdgcn_mfma_f32_16x16x16bf16_1k(ke, qf1, zero, 0,0,0); \
    float4v s1o = __builtin_amdgcn_mfma_f32_16x16x16bf16_1k(ko, qf1, zero, 0,0,0); \
    float p0e0 = fast_exp2(s0e[0]), p0e1 = fast_exp2(s0e[1]);               \
    float p0e2 = fast_exp2(s0e[2]), p0e3 = fast_exp2(s0e[3]);               \
    float p0o0 = fast_exp2(s0o[0]), p0o1 = fast_exp2(s0o[1]);               \
    float p0o2 = fast_exp2(s0o[2]), p0o3 = fast_exp2(s0o[3]);               \
    float p1e0 = fast_exp2(s1e[0]), p1e1 = fast_exp2(s1e[1]);               \
    float p1e2 = fast_exp2(s1e[2]), p1e3 = fast_exp2(s1e[3]);               \
    float p1o0 = fast_exp2(s1o[0]), p1o1 = fast_exp2(s1o[1]);               \
    float p1o2 = fast_exp2(s1o[2]), p1o3 = fast_exp2(s1o[3]);               \
    short4v pb0e = pack4_bf16(p0e0, p0e1, p0e2, p0e3);                      \
    short4v pb0o = pack4_bf16(p0o0, p0o1, p0o2, p0o3);                      \
    short4v pb1e = pack4_bf16(p1e0, p1e1, p1e2, p1e3);                      \
    short4v pb1o = pack4_bf16(p1o0, p1o1, p1o2, p1o3);                      \
    short8v pb0 = __builtin_shufflevector(pb0e, pb0o, 0,1,2,3,4,5,6,7);     \
    short8v pb1 = __builtin_shufflevector(pb1e, pb1o, 0,1,2,3,4,5,6,7);     \
    a0   = __builtin_amdgcn_mfma_f32_16x16x32_bf16(vpr, pb0, a0,   0,0,0);  \
    a1   = __builtin_amdgcn_mfma_f32_16x16x32_bf16(vpr, pb1, a1,   0,0,0);  \
    lac0 = __builtin_amdgcn_mfma_f32_16x16x32_bf16(ones8, pb0, lac0, 0,0,0);\
    lac1 = __builtin_amdgcn_mfma_f32_16x16x32_bf16(ones8, pb1, lac1, 0,0,0);\
    __builtin_amdgcn_s_setprio(0);                                          \
  } while (0)

  // prologue: pair-fragments for iters 0 (A) and 1 (B)
  short8v kA = *(const short8v*)(kp16);
  short8v vA = *(const short8v*)(vp16);
  short8v kB = *(const short8v*)(kp16 + 512);
  short8v vB = *(const short8v*)(vp16 + 512);

  #pragma unroll 4
  for (int it2 = 0; it2 < PITERS/2; ++it2) {
    // prefetch iters 2*it2+2 (A') and 2*it2+3 (B'); benign ws over-read at tail
    int oA = (2*it2 + 2) * 512;
    int oB = (2*it2 + 3) * 512;
    short8v nkA = *(const short8v*)(kp16 + oA);
    short8v nvA = *(const short8v*)(vp16 + oA);
    short8v nkB = *(const short8v*)(kp16 + oB);
    short8v nvB = *(const short8v*)(vp16 + oB);

    ITER(kA, vA);
    ITER(kB, vB);

    kA = nkA; vA = nvA; kB = nkB; vB = nvB;
  }
#undef ITER

  // per-wave partials: a0/a1 rows, lac[0] = full per-quarter l for q=l&15
  float l0 = lac0[0], l1 = lac1[0];

  // combine the 4 quarters: waves 1..3 publish, wave 0 reduces + stores
  if (quart != 0) {
    float* cp = &comb[quart-1][lane][0];
    cp[0] = a0[0]; cp[1] = a0[1]; cp[2] = a0[2]; cp[3] = a0[3];
    cp[4] = a1[0]; cp[5] = a1[1]; cp[6] = a1[2]; cp[7] = a1[3];
    cp[8] = l0;    cp[9] = l1;
  }
  __syncthreads();
  if (quart == 0) {
    float o0[4], o1[4];
    #pragma unroll
    for (int r = 0; r < 4; ++r) { o0[r] = a0[r]; o1[r] = a1[r]; }
    #pragma unroll
    for (int wv = 0; wv < 3; ++wv) {
      const float* cp = &comb[wv][lane][0];
      o0[0] += cp[0]; o0[1] += cp[1]; o0[2] += cp[2]; o0[3] += cp[3];
      o1[0] += cp[4]; o1[1] += cp[5]; o1[2] += cp[6]; o1[3] += cp[7];
      l0 += cp[8];    l1 += cp[9];
    }
    float inv0 = 1.0f / l0, inv1 = 1.0f / l1;

    int b = bh >> 2, h = bh & 3;
    float* ob = out + ((size_t)(b*64 + h*16 + g4)) * NTOK;
    #pragma unroll
    for (int r = 0; r < 4; ++r) {
      ob[(size_t)r*NTOK + qbase      + lr] = o0[r] * inv0;
      ob[(size_t)r*NTOK + qbase + 16 + lr] = o1[r] * inv1;
    }
  }
}

extern "C" void kernel_launch(void* const* d_in, const int* in_sizes, int n_in,
                              void* d_out, int out_size, void* d_ws, size_t ws_size,
                              hipStream_t stream) {
  const float* x    = (const float*)d_in[0];   // (2,64,64,64)
  const float* w    = (const float*)d_in[1];   // (192,64)
  const float* bias = (const float*)d_in[2];   // (192,)
  float* out  = (float*)d_out;                 // (2,64,64,64)
  ushort* wsu = (ushort*)d_ws;                 // 3 MB used (+~2KB over-read pad)

  qkv_proj <<<768,  256, 0, stream>>>(x, w, bias, wsu);
  attn_mfma<<<1024, 256, 0, stream>>>(wsu, out);
}

// Round 22
// 35.596 us; speedup vs baseline: 1.1718x; 1.1718x over previous
//
#include <hip/hip_runtime.h>
#include <hip/hip_bf16.h>

// SpatialAttention2D MFMA v21 == v18 restored (the 35.43 us best).
// r21's A/B proved qkv-2tok was r20's regression; qkv reverted to the v17
// TPT=1 high-occupancy form (grid 1536, 24 waves/CU). attn: v18's
// K=32 PV + ones-MFMA lsum + unroll-4 depth-2 register pipeline.

#define NTOK 4096
#define HD   16
#define BH   8
#define QUART 1024             // keys per wave (key-quarter)
#define PITERS (QUART/32)      // 32 pair-iters (2 chunks of 16 keys each)

typedef __attribute__((ext_vector_type(4))) short short4v;
typedef __attribute__((ext_vector_type(8))) short short8v;
typedef __attribute__((ext_vector_type(4))) float float4v;
typedef __attribute__((ext_vector_type(4))) ushort ushort4v;
typedef __attribute__((ext_vector_type(2))) unsigned uint2v;

__device__ __forceinline__ ushort f2bf(float f) {
  unsigned u = __builtin_bit_cast(unsigned, f);
  u += 0x7fffu + ((u >> 16) & 1u);          // round-to-nearest-even
  return (ushort)(u >> 16);
}

__device__ __forceinline__ float fast_exp2(float x) {
#if __has_builtin(__builtin_amdgcn_exp2f)
  return __builtin_amdgcn_exp2f(x);
#else
  return exp2f(x);
#endif
}

// packed f32x4 -> bf16x4 (RNE) via v_cvt_pk_bf16_f32 (v6b-verified form)
__device__ __forceinline__ short4v pack4_bf16(float a, float b, float c, float d) {
  __hip_bfloat162 lo = __float22bfloat162_rn(make_float2(a, b));
  __hip_bfloat162 hi = __float22bfloat162_rn(make_float2(c, d));
  unsigned ulo, uhi;
  __builtin_memcpy(&ulo, &lo, 4);
  __builtin_memcpy(&uhi, &hi, 4);
  uint2v u = { ulo, uhi };
  return __builtin_bit_cast(short4v, u);
}

// ws layout in ushort elements (3 MB total)
// Qt: [bh][d][n] (transposed).
// Kp (pair-frag): element (key n, d) at unit (n>>5)*512 +
//     ((d>>2)*16 + (n&15))*8 + ((n>>4)&1)*4 + (d&3)
// Vp (pair-frag): element (d, key n) at unit (n>>5)*512 +
//     (((n&15)>>2)*16 + d)*8 + ((n>>4)&1)*4 + (n&3)
// Both: lane l, pair-iter i reads 16B at i*512 + l*8 = [even frag | odd frag].
#define QB_OFF 0
#define KB_OFF ((size_t)BH*NTOK*HD)
#define VT_OFF (2*(size_t)BH*NTOK*HD)

// ---------------------------------------------------------------------------
// Kernel 1: QKV projection, high-occupancy form (byte-identical to v17/v18).
// Grid = 12 gg x 128 tg = 1536 blocks x 256 threads.
//   gg -> (part, head); thread -> token t = tg*64 + (tid&63), d-group
//   dg = tid>>6 (4 channels). w slice (16ch x 64) in LDS, wave-uniform
//   float4 broadcasts; x chunked 16-at-a-time.
// ---------------------------------------------------------------------------
__global__ __launch_bounds__(256) void qkv_proj(
    const float* __restrict__ x, const float* __restrict__ w,
    const float* __restrict__ bias, ushort* __restrict__ wsu) {
  int tg   = blockIdx.x & 127;     // token group; same tg -> same XCD (128%8==0)
  int gg   = blockIdx.x >> 7;      // 0..11: 16-channel slice
  int part = gg >> 2;              // 0=q,1=k,2=v
  int h    = gg & 3;
  int lane = threadIdx.x & 63;
  int dg   = threadIdx.x >> 6;     // 0..3: d-subgroup
  int t    = tg*64 + lane;         // global token 0..8191
  int b    = t >> 12;
  int np   = t & 4095;
  int bh   = b*4 + h;
  const float QSCALE = 0.25f * 1.44269504f;

  __shared__ float4 wls[16][16];   // 16 channels x 64 floats = 4 KB
  __shared__ float  bls[16];

  {
    const float4* wg = reinterpret_cast<const float4*>(w + (size_t)gg*16*64);
    wls[threadIdx.x >> 4][threadIdx.x & 15] = wg[threadIdx.x];
    if (threadIdx.x < 16) bls[threadIdx.x] = bias[gg*16 + threadIdx.x];
  }
  __syncthreads();

  float acc0 = bls[dg*4+0], acc1 = bls[dg*4+1];
  float acc2 = bls[dg*4+2], acc3 = bls[dg*4+3];
  const float* xp = x + ((size_t)b*64)*NTOK + np;

  #pragma unroll
  for (int cc = 0; cc < 4; ++cc) {
    float xr[16];
    #pragma unroll
    for (int i = 0; i < 16; ++i)
      xr[i] = xp[(size_t)(cc*16 + i)*NTOK];
    #pragma unroll
    for (int i4 = 0; i4 < 4; ++i4) {
      float4 w0 = wls[dg*4+0][cc*4+i4];
      float4 w1 = wls[dg*4+1][cc*4+i4];
      float4 w2 = wls[dg*4+2][cc*4+i4];
      float4 w3 = wls[dg*4+3][cc*4+i4];
      acc0 = fmaf(xr[i4*4+0], w0.x, acc0); acc0 = fmaf(xr[i4*4+1], w0.y, acc0);
      acc0 = fmaf(xr[i4*4+2], w0.z, acc0); acc0 = fmaf(xr[i4*4+3], w0.w, acc0);
      acc1 = fmaf(xr[i4*4+0], w1.x, acc1); acc1 = fmaf(xr[i4*4+1], w1.y, acc1);
      acc1 = fmaf(xr[i4*4+2], w1.z, acc1); acc1 = fmaf(xr[i4*4+3], w1.w, acc1);
      acc2 = fmaf(xr[i4*4+0], w2.x, acc2); acc2 = fmaf(xr[i4*4+1], w2.y, acc2);
      acc2 = fmaf(xr[i4*4+2], w2.z, acc2); acc2 = fmaf(xr[i4*4+3], w2.w, acc2);
      acc3 = fmaf(xr[i4*4+0], w3.x, acc3); acc3 = fmaf(xr[i4*4+1], w3.y, acc3);
      acc3 = fmaf(xr[i4*4+2], w3.z, acc3); acc3 = fmaf(xr[i4*4+3], w3.w, acc3);
    }
  }

  int dd0 = dg*4;
  if (part == 0) {                 // Qt [d][n]: 4 scalar stores, lane-coalesced
    ushort* Qt = wsu + QB_OFF + (size_t)bh*HD*NTOK + np;
    Qt[(size_t)(dd0+0)*NTOK] = f2bf(acc0*QSCALE);
    Qt[(size_t)(dd0+1)*NTOK] = f2bf(acc1*QSCALE);
    Qt[(size_t)(dd0+2)*NTOK] = f2bf(acc2*QSCALE);
    Qt[(size_t)(dd0+3)*NTOK] = f2bf(acc3*QSCALE);
  } else if (part == 1) {          // Kp pair-frag: d&3 consecutive -> one 8B store
    size_t idx = (size_t)bh*NTOK*HD + (size_t)(np >> 5)*512
               + ((dd0 >> 2)*16 + (np & 15))*8 + ((np >> 4) & 1)*4;
    ushort4v vv = { f2bf(acc0), f2bf(acc1), f2bf(acc2), f2bf(acc3) };
    *(ushort4v*)(wsu + KB_OFF + idx) = vv;
  } else {                         // Vp pair-frag: 4 scalar stores, 8-unit stride
    size_t base = (size_t)bh*NTOK*HD + (size_t)(np >> 5)*512
                + ((np >> 4) & 1)*4 + (np & 3);
    ushort* Vp = wsu + VT_OFF + base;
    Vp[(((np & 15) >> 2)*16 + dd0+0)*8] = f2bf(acc0);
    Vp[(((np & 15) >> 2)*16 + dd0+1)*8] = f2bf(acc1);
    Vp[(((np & 15) >> 2)*16 + dd0+2)*8] = f2bf(acc2);
    Vp[(((np & 15) >> 2)*16 + dd0+3)*8] = f2bf(acc3);
  }
}

// ---------------------------------------------------------------------------
// Kernel 2: register-direct MFMA flash attention; K=32 PV + ones-MFMA lsum.
// BYTE-IDENTICAL to v18 (35.43 best): #pragma unroll 4 pipeline, depth-2.
// Grid = 8 bh x 128 qblk(32q) = 1024 blocks x 256 threads (4 waves).
// ---------------------------------------------------------------------------
__global__ __launch_bounds__(256, 4) void attn_mfma(
    const ushort* __restrict__ wsu, float* __restrict__ out) {
  const ushort* Qt = wsu + QB_OFF;
  const ushort* Kp = wsu + KB_OFF;
  const ushort* Vp = wsu + VT_OFF;

  int bh    = blockIdx.x >> 7;
  int qblk  = blockIdx.x & 127;
  int tid   = threadIdx.x;
  int quart = tid >> 6;            // 0..3: key-quarter
  int lane  = tid & 63;
  int lr    = lane & 15;
  int g4    = (lane >> 4) << 2;
  int qbase = qblk*32;

  __shared__ float comb[3][64][11];   // 8.4 KB epilogue combine

  const ushort* Qh = Qt + (size_t)bh*HD*NTOK;                       // [d][n]
  const ushort* KhF = Kp + (size_t)bh*NTOK*HD + (size_t)quart*QUART*HD;
  const ushort* VhF = Vp + (size_t)bh*NTOK*HD + (size_t)quart*QUART*HD;

  // Q fragments (B operand): lane l holds Q[q][d=g4..g4+3], q-groups 0/1
  short4v qf0, qf1;
  #pragma unroll
  for (int j = 0; j < 4; ++j) {
    qf0[j] = (short)Qh[(size_t)(g4+j)*NTOK + qbase      + lr];
    qf1[j] = (short)Qh[(size_t)(g4+j)*NTOK + qbase + 16 + lr];
  }

  // per-lane 16B pair-fragment pointers; pair-iter i reads at i*512 (ushorts)
  const ushort* kp16 = KhF + lane*8;
  const ushort* vp16 = VhF + lane*8;

  const short8v ones8 = {(short)0x3F80, (short)0x3F80, (short)0x3F80, (short)0x3F80,
                         (short)0x3F80, (short)0x3F80, (short)0x3F80, (short)0x3F80};

  float4v a0 = {0.f,0.f,0.f,0.f}, a1 = {0.f,0.f,0.f,0.f};
  float4v lac0 = {0.f,0.f,0.f,0.f}, lac1 = {0.f,0.f,0.f,0.f};

#define ITER(kpr, vpr)                                                      \
  do {                                                                      \
    short4v ke = __builtin_shufflevector(kpr, kpr, 0,1,2,3);                \
    short4v ko = __builtin_shufflevector(kpr, kpr, 4,5,6,7);                \
    float4v zero = {0.f,0.f,0.f,0.f};                                       \
    __builtin_amdgcn_s_setprio(1);                                          \
    float4v s0e = __builtin_amdgcn_mfma_f32_16x16x16bf16_1k(ke, qf0, zero, 0,0,0); \
    float4v s0o = __builtin_amdgcn_mfma_f32_16x16x16bf16_1k(ko, qf0, zero, 0,0,0); \
    float4v s1e = __builtin_amdgcn_mfma_f32_16x16x16bf16_1k(ke, qf1, zero, 0,0,0); \
    float4v s1o = __builtin_amdgcn_mfma_f32_16x16x16bf16_1k(ko, qf1, zero, 0,0,0); \
    float p0e0 = fast_exp2(s0e[0]), p0e1 = fast_exp2(s0e[1]);               \
    float p0e2 = fast_exp2(s0e[2]), p0e3 = fast_exp2(s0e[3]);               \
    float p0o0 = fast_exp2(s0o[0]), p0o1 = fast_exp2(s0o[1]);               \
    float p0o2 = fast_exp2(s0o[2]), p0o3 = fast_exp2(s0o[3]);               \
    float p1e0 = fast_exp2(s1e[0]), p1e1 = fast_exp2(s1e[1]);               \
    float p1e2 = fast_exp2(s1e[2]), p1e3 = fast_exp2(s1e[3]);               \
    float p1o0 = fast_exp2(s1o[0]), p1o1 = fast_exp2(s1o[1]);               \
    float p1o2 = fast_exp2(s1o[2]), p1o3 = fast_exp2(s1o[3]);               \
    short4v pb0e = pack4_bf16(p0e0, p0e1, p0e2, p0e3);                      \
    short4v pb0o = pack4_bf16(p0o0, p0o1, p0o2, p0o3);                      \
    short4v pb1e = pack4_bf16(p1e0, p1e1, p1e2, p1e3);                      \
    short4v pb1o = pack4_bf16(p1o0, p1o1, p1o2, p1o3);                      \
    short8v pb0 = __builtin_shufflevector(pb0e, pb0o, 0,1,2,3,4,5,6,7);     \
    short8v pb1 = __builtin_shufflevector(pb1e, pb1o, 0,1,2,3,4,5,6,7);     \
    a0   = __builtin_amdgcn_mfma_f32_16x16x32_bf16(vpr, pb0, a0,   0,0,0);  \
    a1   = __builtin_amdgcn_mfma_f32_16x16x32_bf16(vpr, pb1, a1,   0,0,0);  \
    lac0 = __builtin_amdgcn_mfma_f32_16x16x32_bf16(ones8, pb0, lac0, 0,0,0);\
    lac1 = __builtin_amdgcn_mfma_f32_16x16x32_bf16(ones8, pb1, lac1, 0,0,0);\
    __builtin_amdgcn_s_setprio(0);                                          \
  } while (0)

  // prologue: pair-fragments for iters 0 (A) and 1 (B)
  short8v kA = *(const short8v*)(kp16);
  short8v vA = *(const short8v*)(vp16);
  short8v kB = *(const short8v*)(kp16 + 512);
  short8v vB = *(const short8v*)(vp16 + 512);

  #pragma unroll 4
  for (int it2 = 0; it2 < PITERS/2; ++it2) {
    // prefetch iters 2*it2+2 (A') and 2*it2+3 (B'); benign ws over-read at tail
    int oA = (2*it2 + 2) * 512;
    int oB = (2*it2 + 3) * 512;
    short8v nkA = *(const short8v*)(kp16 + oA);
    short8v nvA = *(const short8v*)(vp16 + oA);
    short8v nkB = *(const short8v*)(kp16 + oB);
    short8v nvB = *(const short8v*)(vp16 + oB);

    ITER(kA, vA);
    ITER(kB, vB);

    kA = nkA; vA = nvA; kB = nkB; vB = nvB;
  }
#undef ITER

  // per-wave partials: a0/a1 rows, lac[0] = full per-quarter l for q=l&15
  float l0 = lac0[0], l1 = lac1[0];

  // combine the 4 quarters: waves 1..3 publish, wave 0 reduces + stores
  if (quart != 0) {
    float* cp = &comb[quart-1][lane][0];
    cp[0] = a0[0]; cp[1] = a0[1]; cp[2] = a0[2]; cp[3] = a0[3];
    cp[4] = a1[0]; cp[5] = a1[1]; cp[6] = a1[2]; cp[7] = a1[3];
    cp[8] = l0;    cp[9] = l1;
  }
  __syncthreads();
  if (quart == 0) {
    float o0[4], o1[4];
    #pragma unroll
    for (int r = 0; r < 4; ++r) { o0[r] = a0[r]; o1[r] = a1[r]; }
    #pragma unroll
    for (int wv = 0; wv < 3; ++wv) {
      const float* cp = &comb[wv][lane][0];
      o0[0] += cp[0]; o0[1] += cp[1]; o0[2] += cp[2]; o0[3] += cp[3];
      o1[0] += cp[4]; o1[1] += cp[5]; o1[2] += cp[6]; o1[3] += cp[7];
      l0 += cp[8];    l1 += cp[9];
    }
    float inv0 = 1.0f / l0, inv1 = 1.0f / l1;

    int b = bh >> 2, h = bh & 3;
    float* ob = out + ((size_t)(b*64 + h*16 + g4)) * NTOK;
    #pragma unroll
    for (int r = 0; r < 4; ++r) {
      ob[(size_t)r*NTOK + qbase      + lr] = o0[r] * inv0;
      ob[(size_t)r*NTOK + qbase + 16 + lr] = o1[r] * inv1;
    }
  }
}

extern "C" void kernel_launch(void* const* d_in, const int* in_sizes, int n_in,
                              void* d_out, int out_size, void* d_ws, size_t ws_size,
                              hipStream_t stream) {
  const float* x    = (const float*)d_in[0];   // (2,64,64,64)
  const float* w    = (const float*)d_in[1];   // (192,64)
  const float* bias = (const float*)d_in[2];   // (192,)
  float* out  = (float*)d_out;                 // (2,64,64,64)
  ushort* wsu = (ushort*)d_ws;                 // 3 MB used (+~2KB over-read pad)

  qkv_proj <<<1536, 256, 0, stream>>>(x, w, bias, wsu);
  attn_mfma<<<1024, 256, 0, stream>>>(wsu, out);
}